// Round 1
// baseline (10.967 us; speedup 1.0000x reference)
//
#include <hip/hip_runtime.h>

// Analytic collapse of the 4-qubit reference circuit: expz(theta) == cos(theta).
// Derivation: amp0[k] = c^(4-p)s^p (p=popcount), permutation Q + sign on MSB
// reduce to (C-S)(C+S) with C=cos^2(theta/2), S=sin^2(theta/2) -> cos(theta).
// Kernel is therefore a pure streaming map: out[i] = cos(in[i]). Memory-bound.

__global__ void __launch_bounds__(256)
QuantumLayer_65481071404620_kernel(const float4* __restrict__ in,
                                   float4* __restrict__ out,
                                   int n4) {
    const int stride = gridDim.x * blockDim.x;
    for (int i = blockIdx.x * blockDim.x + threadIdx.x; i < n4; i += stride) {
        float4 t = in[i];
        float4 r;
        r.x = __cosf(t.x);   // v_cos_f32 path: |err| ~1e-5 for theta ~ N(0,1),
        r.y = __cosf(t.y);   // threshold is 2e-2 -> ample margin
        r.z = __cosf(t.z);
        r.w = __cosf(t.w);
        out[i] = r;
    }
}

// Scalar tail kernel in case n % 4 != 0 (not the case here: 4194304 % 4 == 0,
// but keep the launch robust).
__global__ void __launch_bounds__(64)
QuantumLayer_tail_kernel(const float* __restrict__ in,
                         float* __restrict__ out,
                         int start, int n) {
    int i = start + blockIdx.x * blockDim.x + threadIdx.x;
    if (i < n) out[i] = __cosf(in[i]);
}

extern "C" void kernel_launch(void* const* d_in, const int* in_sizes, int n_in,
                              void* d_out, int out_size, void* d_ws, size_t ws_size,
                              hipStream_t stream) {
    const float* theta = (const float*)d_in[0];
    float* out = (float*)d_out;
    const int n = in_sizes[0];          // 4194304
    const int n4 = n >> 2;

    // Memory-bound: cap grid ~2048 blocks, grid-stride the rest (G11).
    const int block = 256;
    int grid = (n4 + block - 1) / block;
    if (grid > 2048) grid = 2048;
    if (grid < 1) grid = 1;

    QuantumLayer_65481071404620_kernel<<<grid, block, 0, stream>>>(
        (const float4*)theta, (float4*)out, n4);

    const int tail_start = n4 << 2;
    const int tail_n = n - tail_start;
    if (tail_n > 0) {
        QuantumLayer_tail_kernel<<<(tail_n + 63) / 64, 64, 0, stream>>>(
            theta, out, tail_start, n);
    }
}